// Round 3
// baseline (76.341 us; speedup 1.0000x reference)
//
#include <hip/hip_runtime.h>
#include <hip/hip_bf16.h>

// ---------------------------------------------------------------------------
// TT-adapter fused kernel for MI355X (gfx950)
// out = hs + gelu(hs @ W_down + b_down) @ W_up + b_up
// W_down [768,64], W_up [64,768] reconstructed from rank-5 TT cores.
//
// Kernel 0: build bf16 weights in MFMA-fragment-ready layout in d_ws.
// Kernel 1: wave-autonomous fused kernel: each wave owns 16 rows end-to-end,
//           zero barriers, loads stream continuously (latency hidden by TLP+ILP).
// ---------------------------------------------------------------------------

typedef __attribute__((ext_vector_type(8))) short bf16x8;
typedef __attribute__((ext_vector_type(4))) float f32x4;

__device__ __forceinline__ unsigned short f2bf(float f) {
    union { float f; unsigned u; } v; v.f = f;
    unsigned r = (v.u + 0x7FFFu + ((v.u >> 16) & 1u)) >> 16;
    return (unsigned short)r;
}

// Staged TT contraction for one matrix entry (cores in LDS).
__device__ __forceinline__ float tt_entry(
    const float* c0, const float* c1, const float* c2,
    const float* c3, const float* c4,
    int i0, int i1, int i2, int i3, int i4)
{
    float v1[5], v2[5], v3[5];
#pragma unroll
    for (int r2 = 0; r2 < 5; ++r2) {
        float s = 0.f;
#pragma unroll
        for (int r1 = 0; r1 < 5; ++r1)
            s += c0[i0 * 5 + r1] * c1[(r1 * 8 + i1) * 5 + r2];
        v1[r2] = s;
    }
#pragma unroll
    for (int r3 = 0; r3 < 5; ++r3) {
        float s = 0.f;
#pragma unroll
        for (int r2 = 0; r2 < 5; ++r2)
            s += v1[r2] * c2[(r2 * 12 + i2) * 5 + r3];
        v2[r3] = s;
    }
#pragma unroll
    for (int r4 = 0; r4 < 5; ++r4) {
        float s = 0.f;
#pragma unroll
        for (int r3 = 0; r3 < 5; ++r3)
            s += v2[r3] * c3[(r3 * 8 + i3) * 5 + r4];
        v3[r4] = s;
    }
    float w = 0.f;
#pragma unroll
    for (int r4 = 0; r4 < 5; ++r4)
        w += v3[r4] * c4[r4 * 8 + i4];
    return w;
}

// WdFrag[((ks*4+nt)*64 + lane)*8 + j] = Wd[ks*32 + (lane>>4)*8 + j][nt*16 + (lane&15)]
// WuFrag[((s*48+ht)*64 + lane)*8 + j] = Wu[s*32  + (lane>>4)*8 + j][ht*16 + (lane&15)]
__global__ __launch_bounds__(256) void tt_build_frags(
    const float* __restrict__ d0, const float* __restrict__ d1,
    const float* __restrict__ d2, const float* __restrict__ d3,
    const float* __restrict__ d4,
    const float* __restrict__ u0, const float* __restrict__ u1,
    const float* __restrict__ u2, const float* __restrict__ u3,
    const float* __restrict__ u4,
    unsigned short* __restrict__ wdFrag, unsigned short* __restrict__ wuFrag)
{
    __shared__ float cs[1560];
    {
        const float* srcs[10] = { d0, d1, d2, d3, d4, u0, u1, u2, u3, u4 };
        const int sizes[10]   = { 40, 200, 300, 200, 40, 40, 200, 300, 200, 40 };
        const int offs[10]    = { 0, 40, 240, 540, 740, 780, 820, 1020, 1320, 1520 };
#pragma unroll
        for (int c = 0; c < 10; ++c)
            for (int i = threadIdx.x; i < sizes[c]; i += 256)
                cs[offs[c] + i] = srcs[c][i];
    }
    __syncthreads();

    int e = blockIdx.x * 256 + threadIdx.x;   // 0..98303
    bool isUp = (e >= 49152);
    int idx = isUp ? (e - 49152) : e;
    int j    = idx & 7;
    int lane = (idx >> 3) & 63;
    int tile = idx >> 9;                      // 0..95
    int kg = lane >> 4, ln = lane & 15;

    if (!isUp) {
        int ks = tile >> 2, nt = tile & 3;
        int k = ks * 32 + kg * 8 + j;
        int a = nt * 16 + ln;
        int i0 = k / 96, i1 = (k / 12) % 8, i2 = k % 12;
        int i3 = a >> 3, i4 = a & 7;
        float w = tt_entry(cs + 0, cs + 40, cs + 240, cs + 540, cs + 740,
                           i0, i1, i2, i3, i4);
        wdFrag[idx] = f2bf(w);
    } else {
        int s = tile / 48, ht = tile % 48;
        int aIn = s * 32 + kg * 8 + j;
        int h = ht * 16 + ln;
        int i0 = aIn >> 3, i1 = aIn & 7;
        int i2 = h / 64, i3 = (h >> 3) & 7, i4 = h & 7;
        float w = tt_entry(cs + 780, cs + 820, cs + 1020, cs + 1320, cs + 1520,
                           i0, i1, i2, i3, i4);
        wuFrag[idx] = f2bf(w);
    }
}

// ---------------------------------------------------------------------------
// Wave-autonomous fused adapter kernel.
// Block = 256 thr = 4 independent waves; each wave owns 16 rows.
// Per-wave LDS scratch (4608 B): [0,2048) act bf16 (XOR-swizzled);
//   [2048,2048+2*1280) two 16x20-f32 output-transpose tiles (stride 80 B,
//   16B-aligned rows, <=2-way banks).
// Phase 1: down-GEMM K=768, direct global->VGPR A loads, cvt_pk bf16, 4 MFMA/ks.
// Phase 2: up-GEMM over all 48 col-tiles; D-frag -> LDS transpose -> dwordx4
//   residual load + add + dwordx4 store.
// No __syncthreads anywhere.
// ---------------------------------------------------------------------------

__device__ __forceinline__ bf16x8 cvt8(f32x4 a, f32x4 b) {
    union { bf16x8 v; __hip_bfloat162 h[4]; } r;
    r.h[0] = __float22bfloat162_rn(make_float2(a[0], a[1]));
    r.h[1] = __float22bfloat162_rn(make_float2(a[2], a[3]));
    r.h[2] = __float22bfloat162_rn(make_float2(b[0], b[1]));
    r.h[3] = __float22bfloat162_rn(make_float2(b[2], b[3]));
    return r.v;
}

__global__ __launch_bounds__(256, 2) void adapter_fused(
    const float* __restrict__ hs,
    const float* __restrict__ b_down,
    const float* __restrict__ b_up,
    const unsigned short* __restrict__ wdFrag,
    const unsigned short* __restrict__ wuFrag,
    float* __restrict__ out)
{
    __shared__ char lds[4][4608];

    const int t    = threadIdx.x;
    const int lane = t & 63;
    const int w    = t >> 6;
    const int ln   = lane & 15;
    const int kg   = lane >> 4;
    char* myl = lds[w];

    const int wrow0 = blockIdx.x * 64 + w * 16;     // wave's first row
    const float* hsrow = hs + (size_t)(wrow0 + ln) * 768;

    // ---------------- Phase 1: down GEMM (K = 768) ----------------
    f32x4 acc[4];
#pragma unroll
    for (int nt = 0; nt < 4; ++nt) acc[nt] = (f32x4){0.f, 0.f, 0.f, 0.f};

#pragma unroll 8
    for (int ks = 0; ks < 24; ++ks) {
        f32x4 fa = *(const f32x4*)(hsrow + ks * 32 + kg * 8);
        f32x4 fb = *(const f32x4*)(hsrow + ks * 32 + kg * 8 + 4);
        bf16x8 afrag = cvt8(fa, fb);
#pragma unroll
        for (int nt = 0; nt < 4; ++nt) {
            bf16x8 bfrag = *(const bf16x8*)(wdFrag + (((ks * 4 + nt) * 64) + lane) * 8);
            acc[nt] = __builtin_amdgcn_mfma_f32_16x16x32_bf16(afrag, bfrag, acc[nt], 0, 0, 0);
        }
    }

    // bias + exact gelu -> per-wave act buffer (bf16, XOR-swizzled)
#pragma unroll
    for (int nt = 0; nt < 4; ++nt) {
        const float bd = b_down[nt * 16 + ln];
#pragma unroll
        for (int r = 0; r < 4; ++r) {
            const int rr = kg * 4 + r;
            float x = acc[nt][r] + bd;
            float g = 0.5f * x * (1.0f + erff(x * 0.70710678118654752f));
            unsigned off = ((unsigned)(rr * 128 + (nt * 16 + ln) * 2))
                         ^ ((unsigned)((rr & 7) << 4));
            *(__hip_bfloat16*)(myl + off) = __float2bfloat16(g);
        }
    }
    asm volatile("s_waitcnt lgkmcnt(0)" ::: "memory");

    // read act back as A fragments: row = ln, k = s*32 + kg*8 + j
    bf16x8 pa[2];
#pragma unroll
    for (int s = 0; s < 2; ++s) {
        unsigned off = ((unsigned)(ln * 128 + s * 64 + kg * 16))
                     ^ ((unsigned)((ln & 7) << 4));
        pa[s] = *(const bf16x8*)(myl + off);
    }

    // ---------------- Phase 2: up GEMM (48 col-tiles) ----------------
    char* tbuf = myl + 2048;
    const int trow = lane >> 2;            // 0..15
    const int tc   = (lane & 3) * 4;       // 0,4,8,12

#pragma unroll 4
    for (int n2 = 0; n2 < 48; ++n2) {
        char* tb = tbuf + (n2 & 1) * 1280;
        f32x4 a2 = (f32x4){0.f, 0.f, 0.f, 0.f};
#pragma unroll
        for (int s = 0; s < 2; ++s) {
            bf16x8 bfrag = *(const bf16x8*)(wuFrag + (((s * 48 + n2) * 64) + lane) * 8);
            a2 = __builtin_amdgcn_mfma_f32_16x16x32_bf16(pa[s], bfrag, a2, 0, 0, 0);
        }
        // D-frag -> 16x20-f32 tile (row stride 80 B)
#pragma unroll
        for (int r = 0; r < 4; ++r)
            *(float*)(tb + (kg * 4 + r) * 80 + ln * 4) = a2[r];
        asm volatile("s_waitcnt lgkmcnt(0)" ::: "memory");
        // transposed read + residual + bias + store (16 B/lane)
        f32x4 tv = *(const f32x4*)(tb + trow * 80 + tc * 4);
        size_t goff = (size_t)(wrow0 + trow) * 768 + n2 * 16 + tc;
        f32x4 hv = *(const f32x4*)(hs + goff);
        f32x4 bu = *(const f32x4*)(b_up + n2 * 16 + tc);
        f32x4 o;
#pragma unroll
        for (int j = 0; j < 4; ++j) o[j] = tv[j] + hv[j] + bu[j];
        *(f32x4*)(out + goff) = o;
    }
}

extern "C" void kernel_launch(void* const* d_in, const int* in_sizes, int n_in,
                              void* d_out, int out_size, void* d_ws, size_t ws_size,
                              hipStream_t stream) {
    // dict order: hidden_states, b_down, b_up, d0,u0,d1,u1,d2,u2,d3,u3,d4,u4
    const float* hs = (const float*)d_in[0];
    const float* bd = (const float*)d_in[1];
    const float* bu = (const float*)d_in[2];
    const float* d0 = (const float*)d_in[3];
    const float* u0 = (const float*)d_in[4];
    const float* d1 = (const float*)d_in[5];
    const float* u1 = (const float*)d_in[6];
    const float* d2 = (const float*)d_in[7];
    const float* u2 = (const float*)d_in[8];
    const float* d3 = (const float*)d_in[9];
    const float* u3 = (const float*)d_in[10];
    const float* d4 = (const float*)d_in[11];
    const float* u4 = (const float*)d_in[12];

    unsigned short* wdFrag = (unsigned short*)d_ws;            // 49152 bf16
    unsigned short* wuFrag = wdFrag + 49152;                   // 49152 bf16

    tt_build_frags<<<384, 256, 0, stream>>>(d0, d1, d2, d3, d4,
                                            u0, u1, u2, u3, u4,
                                            wdFrag, wuFrag);

    const int rows = 16 * 2048;                // 32768 rows, 64 per block
    adapter_fused<<<rows / 64, 256, 0, stream>>>(hs, bd, bu, wdFrag, wuFrag,
                                                 (float*)d_out);
}

// Round 4
// 65.860 us; speedup vs baseline: 1.1591x; 1.1591x over previous
//
#include <hip/hip_runtime.h>
#include <hip/hip_bf16.h>

// ---------------------------------------------------------------------------
// TT-adapter fused kernel for MI355X (gfx950)
// out = hs + gelu(hs @ W_down + b_down) @ W_up + b_up
// W_down [768,64], W_up [64,768] reconstructed from rank-5 TT cores.
//
// Kernel 0: build bf16 weights in MFMA-fragment-ready layout in d_ws.
// Kernel 1: wave-autonomous fused kernel (zero barriers, no asm waits):
//   each wave owns 16 rows end-to-end.
//   Phase 1: down-GEMM, A streamed global->VGPR, 4 acc tiles.
//   act roundtrip: one 2KB per-wave LDS transpose (D-frag -> A-frag).
//   Phase 2: up-GEMM with SWAPPED operands: mfma(WuFrag, act) so the D
//   fragment is lane-row-local -> f32x4 residual load + f32x4 store.
// ---------------------------------------------------------------------------

typedef __attribute__((ext_vector_type(8))) short bf16x8;
typedef __attribute__((ext_vector_type(4))) float f32x4;

__device__ __forceinline__ unsigned short f2bf(float f) {
    union { float f; unsigned u; } v; v.f = f;
    unsigned r = (v.u + 0x7FFFu + ((v.u >> 16) & 1u)) >> 16;
    return (unsigned short)r;
}

// Staged TT contraction for one matrix entry (cores in LDS).
__device__ __forceinline__ float tt_entry(
    const float* c0, const float* c1, const float* c2,
    const float* c3, const float* c4,
    int i0, int i1, int i2, int i3, int i4)
{
    float v1[5], v2[5], v3[5];
#pragma unroll
    for (int r2 = 0; r2 < 5; ++r2) {
        float s = 0.f;
#pragma unroll
        for (int r1 = 0; r1 < 5; ++r1)
            s += c0[i0 * 5 + r1] * c1[(r1 * 8 + i1) * 5 + r2];
        v1[r2] = s;
    }
#pragma unroll
    for (int r3 = 0; r3 < 5; ++r3) {
        float s = 0.f;
#pragma unroll
        for (int r2 = 0; r2 < 5; ++r2)
            s += v1[r2] * c2[(r2 * 12 + i2) * 5 + r3];
        v2[r3] = s;
    }
#pragma unroll
    for (int r4 = 0; r4 < 5; ++r4) {
        float s = 0.f;
#pragma unroll
        for (int r3 = 0; r3 < 5; ++r3)
            s += v2[r3] * c3[(r3 * 8 + i3) * 5 + r4];
        v3[r4] = s;
    }
    float w = 0.f;
#pragma unroll
    for (int r4 = 0; r4 < 5; ++r4)
        w += v3[r4] * c4[r4 * 8 + i4];
    return w;
}

// WdFrag[((ks*4+nt)*64 + lane)*8 + j] = Wd[ks*32 + (lane>>4)*8 + j][nt*16 + (lane&15)]
// WuFrag[((s*48+ht)*64 + lane)*8 + j] = Wu[s*32  + (lane>>4)*8 + j][ht*16 + (lane&15)]
//   (B-frag of Wu == A-frag of Wu^T, so the same buffer serves the swapped GEMM)
__global__ __launch_bounds__(256) void tt_build_frags(
    const float* __restrict__ d0, const float* __restrict__ d1,
    const float* __restrict__ d2, const float* __restrict__ d3,
    const float* __restrict__ d4,
    const float* __restrict__ u0, const float* __restrict__ u1,
    const float* __restrict__ u2, const float* __restrict__ u3,
    const float* __restrict__ u4,
    unsigned short* __restrict__ wdFrag, unsigned short* __restrict__ wuFrag)
{
    __shared__ float cs[1560];
    {
        const float* srcs[10] = { d0, d1, d2, d3, d4, u0, u1, u2, u3, u4 };
        const int sizes[10]   = { 40, 200, 300, 200, 40, 40, 200, 300, 200, 40 };
        const int offs[10]    = { 0, 40, 240, 540, 740, 780, 820, 1020, 1320, 1520 };
#pragma unroll
        for (int c = 0; c < 10; ++c)
            for (int i = threadIdx.x; i < sizes[c]; i += 256)
                cs[offs[c] + i] = srcs[c][i];
    }
    __syncthreads();

    int e = blockIdx.x * 256 + threadIdx.x;   // 0..98303
    bool isUp = (e >= 49152);
    int idx = isUp ? (e - 49152) : e;
    int j    = idx & 7;
    int lane = (idx >> 3) & 63;
    int tile = idx >> 9;                      // 0..95
    int kg = lane >> 4, ln = lane & 15;

    if (!isUp) {
        int ks = tile >> 2, nt = tile & 3;
        int k = ks * 32 + kg * 8 + j;
        int a = nt * 16 + ln;
        int i0 = k / 96, i1 = (k / 12) % 8, i2 = k % 12;
        int i3 = a >> 3, i4 = a & 7;
        float w = tt_entry(cs + 0, cs + 40, cs + 240, cs + 540, cs + 740,
                           i0, i1, i2, i3, i4);
        wdFrag[idx] = f2bf(w);
    } else {
        int s = tile / 48, ht = tile % 48;
        int aIn = s * 32 + kg * 8 + j;
        int h = ht * 16 + ln;
        int i0 = aIn >> 3, i1 = aIn & 7;
        int i2 = h / 64, i3 = (h >> 3) & 7, i4 = h & 7;
        float w = tt_entry(cs + 780, cs + 820, cs + 1020, cs + 1320, cs + 1520,
                           i0, i1, i2, i3, i4);
        wuFrag[idx] = f2bf(w);
    }
}

__device__ __forceinline__ bf16x8 cvt8(f32x4 a, f32x4 b) {
    union { bf16x8 v; __hip_bfloat162 h[4]; } r;
    r.h[0] = __float22bfloat162_rn(make_float2(a[0], a[1]));
    r.h[1] = __float22bfloat162_rn(make_float2(a[2], a[3]));
    r.h[2] = __float22bfloat162_rn(make_float2(b[0], b[1]));
    r.h[3] = __float22bfloat162_rn(make_float2(b[2], b[3]));
    return r.v;
}

// ---------------------------------------------------------------------------
// Wave-autonomous fused kernel. 512 blocks x 256 thr (4 waves); wave owns
// 16 rows. LDS: 2KB/wave act buffer only. No __syncthreads, no asm waits.
// ---------------------------------------------------------------------------
__global__ __launch_bounds__(256) void adapter_fused(
    const float* __restrict__ hs,
    const float* __restrict__ b_down,
    const float* __restrict__ b_up,
    const unsigned short* __restrict__ wdFrag,
    const unsigned short* __restrict__ wuFrag,
    float* __restrict__ out)
{
    __shared__ char act_s[4][2048];

    const int t    = threadIdx.x;
    const int lane = t & 63;
    const int w    = t >> 6;
    const int ln   = lane & 15;
    const int kg   = lane >> 4;
    char* myl = act_s[w];

    const int wrow0 = blockIdx.x * 64 + w * 16;          // wave's first row
    const float* hsrow = hs + (size_t)(wrow0 + ln) * 768 + kg * 8;

    // ---------------- Phase 1: down GEMM (K = 768) ----------------
    f32x4 acc[4];
#pragma unroll
    for (int nt = 0; nt < 4; ++nt) acc[nt] = (f32x4){0.f, 0.f, 0.f, 0.f};

#pragma unroll 4
    for (int ks = 0; ks < 24; ++ks) {
        f32x4 fa = *(const f32x4*)(hsrow + ks * 32);
        f32x4 fb = *(const f32x4*)(hsrow + ks * 32 + 4);
        bf16x8 afrag = cvt8(fa, fb);
#pragma unroll
        for (int nt = 0; nt < 4; ++nt) {
            bf16x8 bfrag = *(const bf16x8*)(wdFrag + (ks * 4 + nt) * 512 + lane * 8);
            acc[nt] = __builtin_amdgcn_mfma_f32_16x16x32_bf16(afrag, bfrag, acc[nt], 0, 0, 0);
        }
    }

    // bias + exact gelu -> per-wave act buffer (bf16, XOR-swizzled rows)
#pragma unroll
    for (int nt = 0; nt < 4; ++nt) {
        const float bd = b_down[nt * 16 + ln];
#pragma unroll
        for (int r = 0; r < 4; ++r) {
            const int rr = kg * 4 + r;              // act row (local)
            const int a  = nt * 16 + ln;            // act col
            float x = acc[nt][r] + bd;
            float g = 0.5f * x * (1.0f + erff(x * 0.70710678118654752f));
            unsigned off = ((unsigned)(rr * 128 + a * 2)) ^ ((unsigned)((rr & 7) << 4));
            *(unsigned short*)(myl + off) = f2bf(g);
        }
    }
    // compiler inserts the lgkmcnt for this same-buffer dependency
    bf16x8 pa[2];
#pragma unroll
    for (int s = 0; s < 2; ++s) {
        unsigned off = ((unsigned)(ln * 128 + s * 64 + kg * 16))
                     ^ ((unsigned)((ln & 7) << 4));
        pa[s] = *(const bf16x8*)(myl + off);
    }

    // ---------------- Phase 2: up GEMM, swapped operands ----------------
    // D[m][n]: m = h offset (kg*4+r), n = row (ln)  ->  lane-row-local f32x4
    const float* hvrow = hs  + (size_t)(wrow0 + ln) * 768 + kg * 4;
    float*       orow  = out + (size_t)(wrow0 + ln) * 768 + kg * 4;
    const float* burow = b_up + kg * 4;

#pragma unroll 6
    for (int ht = 0; ht < 48; ++ht) {
        f32x4 a2 = (f32x4){0.f, 0.f, 0.f, 0.f};
#pragma unroll
        for (int s = 0; s < 2; ++s) {
            bf16x8 wfrag = *(const bf16x8*)(wuFrag + (s * 48 + ht) * 512 + lane * 8);
            // swapped: A = Wu^T tile, B = act rows
            a2 = __builtin_amdgcn_mfma_f32_16x16x32_bf16(wfrag, pa[s], a2, 0, 0, 0);
        }
        f32x4 hv = *(const f32x4*)(hvrow + ht * 16);
        f32x4 bu = *(const f32x4*)(burow + ht * 16);
        f32x4 o;
#pragma unroll
        for (int j = 0; j < 4; ++j) o[j] = a2[j] + hv[j] + bu[j];
        *(f32x4*)(orow + ht * 16) = o;
    }
}

extern "C" void kernel_launch(void* const* d_in, const int* in_sizes, int n_in,
                              void* d_out, int out_size, void* d_ws, size_t ws_size,
                              hipStream_t stream) {
    // dict order: hidden_states, b_down, b_up, d0,u0,d1,u1,d2,u2,d3,u3,d4,u4
    const float* hs = (const float*)d_in[0];
    const float* bd = (const float*)d_in[1];
    const float* bu = (const float*)d_in[2];
    const float* d0 = (const float*)d_in[3];
    const float* u0 = (const float*)d_in[4];
    const float* d1 = (const float*)d_in[5];
    const float* u1 = (const float*)d_in[6];
    const float* d2 = (const float*)d_in[7];
    const float* u2 = (const float*)d_in[8];
    const float* d3 = (const float*)d_in[9];
    const float* u3 = (const float*)d_in[10];
    const float* d4 = (const float*)d_in[11];
    const float* u4 = (const float*)d_in[12];

    unsigned short* wdFrag = (unsigned short*)d_ws;            // 49152 bf16
    unsigned short* wuFrag = wdFrag + 49152;                   // 49152 bf16

    tt_build_frags<<<384, 256, 0, stream>>>(d0, d1, d2, d3, d4,
                                            u0, u1, u2, u3, u4,
                                            wdFrag, wuFrag);

    const int rows = 16 * 2048;                // 32768 rows, 64 per block
    adapter_fused<<<rows / 64, 256, 0, stream>>>(hs, bd, bu, wdFrag, wuFrag,
                                                 (float*)d_out);
}